// Round 10
// baseline (64.449 us; speedup 1.0000x reference)
//
#include <hip/hip_runtime.h>
#include <hip/hip_bf16.h>

// Problem constants (match reference)
#define CIN_  128
#define H_    28
#define W_    28
#define COUT_ 32
#define B_    512
// GEMM view per (b,h): Y[32 x 28] = Wm[32 x 384] * Xwin[384 x 28]
// K order: kappa = tap*128 + channel, chunked in 12 chunks of 32.

typedef __attribute__((ext_vector_type(8))) short short8;  // 8 bf16 in 4 VGPRs
typedef __attribute__((ext_vector_type(4))) float f32x4;

__device__ __forceinline__ unsigned short f2bfu(float f) {
    union { __hip_bfloat16 h; unsigned short s; } u;
    u.h = __float2bfloat16(f);                 // RNE, single HW cvt
    return u.s;
}
__device__ __forceinline__ short f2bf(float f) { return (short)f2bfu(f); }

// ---------------------------------------------------------------------------
// Pre-pass: build bf16 A-fragments of Wm in d_ws.
// Fragment f = mt*12 + kc  (mt: 0..1 M-tile of 16 couts, kc: 0..11 K-chunk of 32)
// Element (lane l, slot j): Wm[jo = mt*16 + (l&15)][i = (kc&3)*32 + (l>>4)*8 + j][tap = kc>>2]
// Stored flat: ws[f*512 + l*8 + j]  -> lane l loads 16B at f*1024 + l*16 bytes.
// ---------------------------------------------------------------------------
__global__ void prep_w_kernel(const float* __restrict__ w, short* __restrict__ wsA) {
    int t = blockIdx.x * 256 + threadIdx.x;      // 24*512 = 12288 threads
    int frag = t >> 9;
    int rem  = t & 511;
    int l = rem >> 3;
    int j = rem & 7;
    int mt = frag / 12;
    int kc = frag % 12;
    int tap = kc >> 2;
    int i  = (kc & 3) * 32 + (l >> 4) * 8 + j;
    int jo = mt * 16 + (l & 15);
    wsA[t] = f2bf(w[(jo * CIN_ + i) * 3 + tap]);
}

// ---------------------------------------------------------------------------
// Main kernel v10 = R9 + nt-outer GEMM with stores interleaved mid-kernel.
// grid (7, 512), block 256 (4 waves). Wave wv computes row h = hg*4 + wv.
// Staging identical to R9 (packed b32 writes, hl-aware bank swizzle).
// GEMM is nt-OUTER: for each N-tile, run the full 12-chunk K loop (24 B-frag
// ds_read_b128 total - unchanged), then immediately store that N-tile's 8
// dwords. This spreads the output write stream into the compute phase
// (de-bursting HBM demand) instead of emitting all 51 MB grid-wide in
// end-of-block clumps. A-fragments are reloaded per (nt, half) from the
// 24-KB L2-resident wsA table (cheap); live regs: 24 afrag + 8 acc.
// LDS word layout (int units, row-buffer hl):
//   word(wt, c) at  wt*64 + (((c>>2) ^ (wt&15) ^ hl) << 2 | (c&3))
// Read side (wave wv = hl): B-frag chunk cch of row wtc is the b128 at short
// index  wtc*128 + ((cch ^ (wtc&15) ^ wv) << 3).
// wt = w + tap (w_real = wt-1). Rows 0,29 zeroed (padding). B-reads with
// wt in 30..33 feed discarded cols (wcol >= 28); clamp to 29.
// ---------------------------------------------------------------------------
template<bool USE_WS>
__global__ __launch_bounds__(256, 5)
void conv_kernel(const float* __restrict__ x, const float* __restrict__ w,
                 const short* __restrict__ wsA, float* __restrict__ out) {
    __shared__ short lds[4][30 * CIN_];          // 4 x 7680 B = 30720 B
    const int tid = threadIdx.x;
    const int wv  = tid >> 6;
    const int l   = tid & 63;
    const int hg  = blockIdx.x;                  // 0..6
    const int b   = blockIdx.y;                  // 0..511
    const int h0  = hg * 4;

    const float* xb = x + (size_t)b * (CIN_ * H_ * W_);

    // ---- zero pad rows wt=0 and wt=29 in this wave's buffer ----
    {
        int s   = (tid & 63) * 4;                // 0..252
        int row = (s >= 128) ? 29 : 0;
        int c   = s & 127;
        *reinterpret_cast<ulong1*>(&lds[wv][row * CIN_ + c]) = ulong1{0};
    }

    // ---- staging loads: 64 channel-pairs x 28 quads; 2 f32x4 per thread-iter
    f32x4 v0[7], v1[7];
#pragma unroll
    for (int it = 0; it < 7; ++it) {
        int f4 = it * 256 + tid;                 // 0..1791
        int c  = f4 / 28;                        // channel pair 0..63
        int q  = f4 % 28;                        // quad within 448-B segment
        const float* p = xb + (2 * c) * (H_ * W_) + h0 * W_ + q * 4;
        v0[it] = *reinterpret_cast<const f32x4*>(p);
        v1[it] = *reinterpret_cast<const f32x4*>(p + H_ * W_);
    }

    // ---- packed cvt + b32 scatter into LDS (hl-aware swizzle) ----
#pragma unroll
    for (int it = 0; it < 7; ++it) {
        int f4 = it * 256 + tid;
        int c  = f4 / 28;
        int q  = f4 % 28;
        int hl = q / 7;                          // local row 0..3
        int w4 = q % 7;
        int* buf = reinterpret_cast<int*>(&lds[hl][0]);
#pragma unroll
        for (int e = 0; e < 4; ++e) {
            int wt  = w4 * 4 + e + 1;            // 1..28
            int idx = wt * 64 + ((((c >> 2) ^ (wt & 15) ^ hl) << 2) | (c & 3));
            unsigned word = (unsigned)f2bfu(v0[it][e]) |
                            ((unsigned)f2bfu(v1[it][e]) << 16);
            buf[idx] = (int)word;
        }
    }

    // ---- A fragments for (nt=0, half=0): ISSUE before the barrier ----
    short8 a0[6], a1[6];
    if (USE_WS) {
#pragma unroll
        for (int k6 = 0; k6 < 6; ++k6) {
            a0[k6] = *reinterpret_cast<const short8*>(wsA + k6 * 512 + l * 8);
            a1[k6] = *reinterpret_cast<const short8*>(wsA + (12 + k6) * 512 + l * 8);
        }
    } else {
#pragma unroll
        for (int k6 = 0; k6 < 6; ++k6) {
            int tap = k6 >> 2;
            int ib  = (k6 & 3) * 32 + (l >> 4) * 8;
#pragma unroll
            for (int j = 0; j < 8; ++j) {
                a0[k6][j] = f2bf(w[((l & 15) * CIN_ + ib + j) * 3 + tap]);
                a1[k6][j] = f2bf(w[((16 + (l & 15)) * CIN_ + ib + j) * 3 + tap]);
            }
        }
    }
    __syncthreads();   // drains lgkm (staging) AND vmcnt (a-frags) for free

    // ---- per-wave GEMM, nt-OUTER, stores interleaved per N-tile ----
    short* wbuf = lds[wv];
    const int h  = h0 + wv;
    const int ho = (h + 1 == H_) ? 0 : (h + 1);
    float* ob = out + (size_t)b * (COUT_ * H_ * W_) + ho * W_;

#pragma unroll
    for (int nt = 0; nt < 2; ++nt) {
        f32x4 acc0, acc1;
#pragma unroll
        for (int q = 0; q < 4; ++q) { acc0[q] = 0.0f; acc1[q] = 0.0f; }

#pragma unroll
        for (int half = 0; half < 2; ++half) {
            if (nt + half > 0) {                 // (0,0) preloaded above
                if (USE_WS) {
#pragma unroll
                    for (int k6 = 0; k6 < 6; ++k6) {
                        int kc = half * 6 + k6;
                        a0[k6] = *reinterpret_cast<const short8*>(wsA + kc * 512 + l * 8);
                        a1[k6] = *reinterpret_cast<const short8*>(wsA + (12 + kc) * 512 + l * 8);
                    }
                } else {
#pragma unroll
                    for (int k6 = 0; k6 < 6; ++k6) {
                        int kc  = half * 6 + k6;
                        int tap = kc >> 2;
                        int ib  = (kc & 3) * 32 + (l >> 4) * 8;
#pragma unroll
                        for (int j = 0; j < 8; ++j) {
                            a0[k6][j] = f2bf(w[((l & 15) * CIN_ + ib + j) * 3 + tap]);
                            a1[k6][j] = f2bf(w[((16 + (l & 15)) * CIN_ + ib + j) * 3 + tap]);
                        }
                    }
                }
            }
#pragma unroll
            for (int k6 = 0; k6 < 6; ++k6) {
                int kc  = half * 6 + k6;
                int tap = kc >> 2;
                int cch = (kc & 3) * 4 + (l >> 4);   // chunk of lane's 8 channels
                int wt  = nt * 16 + (l & 15) + tap;  // 0..33
                int wtc = wt > 29 ? 29 : wt;         // rows >29 feed dead cols
                const short8 bfrag = *reinterpret_cast<const short8*>(
                    &wbuf[wtc * CIN_ + ((cch ^ (wtc & 15) ^ wv) << 3)]);
                acc0 = __builtin_amdgcn_mfma_f32_16x16x32_bf16(a0[k6], bfrag, acc0, 0, 0, 0);
                acc1 = __builtin_amdgcn_mfma_f32_16x16x32_bf16(a1[k6], bfrag, acc1, 0, 0, 0);
            }
        }

        // ---- store this N-tile now (spreads the write stream) ----
        {
            int wcol = nt * 16 + (l & 15);
            if (wcol < W_) {
                int jb = (l >> 4) * 4;           // row group base within M-tile
#pragma unroll
                for (int rr = 0; rr < 4; ++rr) {
                    ob[(jb + rr) * (H_ * W_) + wcol]        = acc0[rr];
                    ob[(16 + jb + rr) * (H_ * W_) + wcol]   = acc1[rr];
                }
            }
        }
    }
}

extern "C" void kernel_launch(void* const* d_in, const int* in_sizes, int n_in,
                              void* d_out, int out_size, void* d_ws, size_t ws_size,
                              hipStream_t stream) {
    (void)in_sizes; (void)n_in; (void)out_size;
    const float* x = (const float*)d_in[0];
    const float* w = (const float*)d_in[1];
    float* out = (float*)d_out;

    if (ws_size >= (size_t)(24 * 512 * sizeof(short))) {
        short* wsA = (short*)d_ws;
        prep_w_kernel<<<dim3(48), dim3(256), 0, stream>>>(w, wsA);
        conv_kernel<true><<<dim3(7, 512), dim3(256), 0, stream>>>(x, w, wsA, out);
    } else {
        conv_kernel<false><<<dim3(7, 512), dim3(256), 0, stream>>>(x, w, (const short*)nullptr, out);
    }
}